// Round 1
// baseline (187.535 us; speedup 1.0000x reference)
//
#include <hip/hip_runtime.h>

#define PP 50
#define TPB 256
#define NBATCH 2048

static constexpr float EPSF = 1e-5f;
static constexpr double ETOT = 5120000.0;   // B * P * P

static __device__ __forceinline__ float lrelu(float x) {
    return fmaxf(x, 0.0f) + 0.01f * fminf(x, 0.0f);
}

// ---------------- Pass 1: y1 = mlp_in @ W1^T + b1 ; accumulate sum/sumsq ----
__global__ __launch_bounds__(TPB) void pass1_kernel(
    const float* __restrict__ feat, const float* __restrict__ ang,
    const float* __restrict__ W1, const float* __restrict__ b1,
    double* __restrict__ acc)
{
    __shared__ float4 nd[PP];
    __shared__ float sW[25], sb[5];
    __shared__ float red[4][10];
    const int t = threadIdx.x;
    const int base = blockIdx.x * PP;

    if (t < PP) {
        float f  = feat[base + t];
        float br = ang[2*(base+t)];
        float bi = ang[2*(base+t)+1];
        nd[t] = make_float4(f, br, bi, 1.0f / (br*br + bi*bi));
    }
    if (t < 25) sW[t] = W1[t];
    if (t < 5)  sb[t] = b1[t];
    __syncthreads();

    float a[10];
#pragma unroll
    for (int k = 0; k < 10; ++k) a[k] = 0.0f;

    if (t < 250) {
        const int pi = t / 5;
        const int s  = t - pi*5;
        const float4 ni = nd[pi];
        const float fi = ni.x, ar = ni.y, ai = ni.z;
        for (int q = 0; q < 10; ++q) {
            const float4 nj = nd[s*10 + q];
            const float fj = nj.x, br = nj.y, bi = nj.z, inv = nj.w;
            const float dr = (ar*br + ai*bi) * inv;
            const float dm = (ai*br - ar*bi) * inv;
            const float df = fj - fi;
#pragma unroll
            for (int o = 0; o < 5; ++o) {
                float y = sb[o];
                y = fmaf(sW[o*5+0], fi, y);
                y = fmaf(sW[o*5+1], fj, y);
                y = fmaf(sW[o*5+2], df, y);
                y = fmaf(sW[o*5+3], dr, y);
                y = fmaf(sW[o*5+4], dm, y);
                a[o]   += y;
                a[5+o]  = fmaf(y, y, a[5+o]);
            }
        }
    }

#pragma unroll
    for (int k = 0; k < 10; ++k) {
        float v = a[k];
#pragma unroll
        for (int off = 32; off > 0; off >>= 1) v += __shfl_down(v, off, 64);
        a[k] = v;
    }
    const int lane = t & 63, wv = t >> 6;
    if (lane == 0) {
#pragma unroll
        for (int k = 0; k < 10; ++k) red[wv][k] = a[k];
    }
    __syncthreads();
    if (t < 10) {
        atomicAdd(&acc[t], (double)(red[0][t] + red[1][t] + red[2][t] + red[3][t]));
    }
}

// ---------------- Pass 2: h1 = lrelu(BN1(y1)); y2 = h1 @ W2^T + b2 ; stats --
__global__ __launch_bounds__(TPB) void pass2_kernel(
    const float* __restrict__ feat, const float* __restrict__ ang,
    const float* __restrict__ W1, const float* __restrict__ b1,
    const float* __restrict__ g1, const float* __restrict__ bt1,
    const float* __restrict__ W2, const float* __restrict__ b2,
    double* __restrict__ acc)
{
    __shared__ float4 nd[PP];
    __shared__ float sW1[25], sb1[5], sW2[25], sb2[5];
    __shared__ float sc1[5], sh1[5];
    __shared__ float red[4][10];
    const int t = threadIdx.x;
    const int base = blockIdx.x * PP;

    if (t < PP) {
        float f  = feat[base + t];
        float br = ang[2*(base+t)];
        float bi = ang[2*(base+t)+1];
        nd[t] = make_float4(f, br, bi, 1.0f / (br*br + bi*bi));
    }
    if (t < 25) { sW1[t] = W1[t]; sW2[t] = W2[t]; }
    if (t < 5) {
        sb1[t] = b1[t]; sb2[t] = b2[t];
        double mu  = acc[t]   / ETOT;
        double var = acc[5+t] / ETOT - mu * mu;
        float s = g1[t] * rsqrtf((float)var + EPSF);
        sc1[t] = s;
        sh1[t] = bt1[t] - (float)mu * s;
    }
    __syncthreads();

    float a[10];
#pragma unroll
    for (int k = 0; k < 10; ++k) a[k] = 0.0f;

    if (t < 250) {
        const int pi = t / 5;
        const int s  = t - pi*5;
        const float4 ni = nd[pi];
        const float fi = ni.x, ar = ni.y, ai = ni.z;
        for (int q = 0; q < 10; ++q) {
            const float4 nj = nd[s*10 + q];
            const float fj = nj.x, br = nj.y, bi = nj.z, inv = nj.w;
            const float dr = (ar*br + ai*bi) * inv;
            const float dm = (ai*br - ar*bi) * inv;
            const float df = fj - fi;
            float h1[5];
#pragma unroll
            for (int o = 0; o < 5; ++o) {
                float y = sb1[o];
                y = fmaf(sW1[o*5+0], fi, y);
                y = fmaf(sW1[o*5+1], fj, y);
                y = fmaf(sW1[o*5+2], df, y);
                y = fmaf(sW1[o*5+3], dr, y);
                y = fmaf(sW1[o*5+4], dm, y);
                h1[o] = lrelu(fmaf(y, sc1[o], sh1[o]));
            }
#pragma unroll
            for (int o = 0; o < 5; ++o) {
                float y = sb2[o];
                y = fmaf(sW2[o*5+0], h1[0], y);
                y = fmaf(sW2[o*5+1], h1[1], y);
                y = fmaf(sW2[o*5+2], h1[2], y);
                y = fmaf(sW2[o*5+3], h1[3], y);
                y = fmaf(sW2[o*5+4], h1[4], y);
                a[o]   += y;
                a[5+o]  = fmaf(y, y, a[5+o]);
            }
        }
    }

#pragma unroll
    for (int k = 0; k < 10; ++k) {
        float v = a[k];
#pragma unroll
        for (int off = 32; off > 0; off >>= 1) v += __shfl_down(v, off, 64);
        a[k] = v;
    }
    const int lane = t & 63, wv = t >> 6;
    if (lane == 0) {
#pragma unroll
        for (int k = 0; k < 10; ++k) red[wv][k] = a[k];
    }
    __syncthreads();
    if (t < 10) {
        atomicAdd(&acc[10 + t], (double)(red[0][t] + red[1][t] + red[2][t] + red[3][t]));
    }
}

// ---- Pass 3: full MLP, mean-aggregate y3 per dst, rotate, write output -----
__global__ __launch_bounds__(TPB) void pass3_kernel(
    const float* __restrict__ pt,
    const float* __restrict__ feat, const float* __restrict__ ang,
    const float* __restrict__ W1, const float* __restrict__ b1,
    const float* __restrict__ g1, const float* __restrict__ bt1,
    const float* __restrict__ W2, const float* __restrict__ b2,
    const float* __restrict__ g2, const float* __restrict__ bt2,
    const float* __restrict__ W3, const float* __restrict__ b3,
    const double* __restrict__ acc, float* __restrict__ out)
{
    __shared__ float4 nd[PP];
    __shared__ float spt[PP];
    __shared__ float sW1[25], sb1[5], sW2[25], sb2[5], sW3[25], sb3[5];
    __shared__ float sc1[5], sh1[5], sc2[5], sh2[5];
    __shared__ float part[250][5];
    const int t = threadIdx.x;
    const int base = blockIdx.x * PP;

    if (t < PP) {
        float f  = feat[base + t];
        float br = ang[2*(base+t)];
        float bi = ang[2*(base+t)+1];
        nd[t] = make_float4(f, br, bi, 1.0f / (br*br + bi*bi));
        spt[t] = pt[base + t];
    }
    if (t < 25) { sW1[t] = W1[t]; sW2[t] = W2[t]; sW3[t] = W3[t]; }
    if (t < 5) {
        sb1[t] = b1[t]; sb2[t] = b2[t]; sb3[t] = b3[t];
        double mu1  = acc[t]    / ETOT;
        double var1 = acc[5+t]  / ETOT - mu1 * mu1;
        float s1 = g1[t] * rsqrtf((float)var1 + EPSF);
        sc1[t] = s1; sh1[t] = bt1[t] - (float)mu1 * s1;
        double mu2  = acc[10+t] / ETOT;
        double var2 = acc[15+t] / ETOT - mu2 * mu2;
        float s2 = g2[t] * rsqrtf((float)var2 + EPSF);
        sc2[t] = s2; sh2[t] = bt2[t] - (float)mu2 * s2;
    }
    __syncthreads();

    float a[5];
#pragma unroll
    for (int k = 0; k < 5; ++k) a[k] = 0.0f;

    if (t < 250) {
        const int pi = t / 5;
        const int s  = t - pi*5;
        const float4 ni = nd[pi];
        const float fi = ni.x, ar = ni.y, ai = ni.z;
        for (int q = 0; q < 10; ++q) {
            const float4 nj = nd[s*10 + q];
            const float fj = nj.x, br = nj.y, bi = nj.z, inv = nj.w;
            const float dr = (ar*br + ai*bi) * inv;
            const float dm = (ai*br - ar*bi) * inv;
            const float df = fj - fi;
            float h1[5], h2[5];
#pragma unroll
            for (int o = 0; o < 5; ++o) {
                float y = sb1[o];
                y = fmaf(sW1[o*5+0], fi, y);
                y = fmaf(sW1[o*5+1], fj, y);
                y = fmaf(sW1[o*5+2], df, y);
                y = fmaf(sW1[o*5+3], dr, y);
                y = fmaf(sW1[o*5+4], dm, y);
                h1[o] = lrelu(fmaf(y, sc1[o], sh1[o]));
            }
#pragma unroll
            for (int o = 0; o < 5; ++o) {
                float y = sb2[o];
                y = fmaf(sW2[o*5+0], h1[0], y);
                y = fmaf(sW2[o*5+1], h1[1], y);
                y = fmaf(sW2[o*5+2], h1[2], y);
                y = fmaf(sW2[o*5+3], h1[3], y);
                y = fmaf(sW2[o*5+4], h1[4], y);
                h2[o] = lrelu(fmaf(y, sc2[o], sh2[o]));
            }
#pragma unroll
            for (int o = 0; o < 5; ++o) {
                float y = sb3[o];
                y = fmaf(sW3[o*5+0], h2[0], y);
                y = fmaf(sW3[o*5+1], h2[1], y);
                y = fmaf(sW3[o*5+2], h2[2], y);
                y = fmaf(sW3[o*5+3], h2[3], y);
                y = fmaf(sW3[o*5+4], h2[4], y);
                a[o] += y;
            }
        }
    }

    if (t < 250) {
#pragma unroll
        for (int c = 0; c < 5; ++c) part[t][c] = a[c];
    }
    __syncthreads();

    if (t < PP) {
        float m[5];
#pragma unroll
        for (int c = 0; c < 5; ++c) {
            m[c] = (part[5*t][c] + part[5*t+1][c] + part[5*t+2][c] +
                    part[5*t+3][c] + part[5*t+4][c]) * 0.02f;
        }
        const int d = base + t;
        const float4 ni = nd[t];
        const float zr = ni.y, zi = ni.z;
        float ss, cc;
        sincosf(6.2831853071795865f * m[4], &ss, &cc);
        float* o = out + (size_t)d * 7;
        o[0] = spt[t];
        o[1] = m[0];
        o[2] = m[1];
        o[3] = m[2];
        o[4] = m[3];
        o[5] = cc * zr - ss * zi;
        o[6] = cc * zi + ss * zr;
    }
}

extern "C" void kernel_launch(void* const* d_in, const int* in_sizes, int n_in,
                              void* d_out, int out_size, void* d_ws, size_t ws_size,
                              hipStream_t stream)
{
    const float* pt   = (const float*)d_in[0];
    const float* feat = (const float*)d_in[1];
    const float* ang  = (const float*)d_in[2];
    const float* W1   = (const float*)d_in[3];
    const float* b1   = (const float*)d_in[4];
    const float* g1   = (const float*)d_in[5];
    const float* bt1  = (const float*)d_in[6];
    const float* W2   = (const float*)d_in[7];
    const float* b2   = (const float*)d_in[8];
    const float* g2   = (const float*)d_in[9];
    const float* bt2  = (const float*)d_in[10];
    const float* W3   = (const float*)d_in[11];
    const float* b3   = (const float*)d_in[12];
    // d_in[13] = edge_index: structure is closed-form (dst=b*P+pi, src=b*P+pj), unused.
    float* out  = (float*)d_out;
    double* acc = (double*)d_ws;   // [0:5] sum1, [5:10] sq1, [10:15] sum2, [15:20] sq2

    hipMemsetAsync(d_ws, 0, 20 * sizeof(double), stream);
    pass1_kernel<<<NBATCH, TPB, 0, stream>>>(feat, ang, W1, b1, acc);
    pass2_kernel<<<NBATCH, TPB, 0, stream>>>(feat, ang, W1, b1, g1, bt1, W2, b2, acc);
    pass3_kernel<<<NBATCH, TPB, 0, stream>>>(pt, feat, ang, W1, b1, g1, bt1, W2, b2,
                                             g2, bt2, W3, b3, acc, out);
}

// Round 2
// 151.636 us; speedup vs baseline: 1.2367x; 1.2367x over previous
//
#include <hip/hip_runtime.h>

#define PP 50
#define TPB 256
#define NBATCH 2048
#define NCOPY 64   // contention-spreading copies for stat atomics

static constexpr float EPSF = 1e-5f;
static constexpr double ETOT = 5120000.0;   // B * P * P

static __device__ __forceinline__ float lrelu(float x) {
    return fmaxf(x, 0.0f) + 0.01f * fminf(x, 0.0f);
}

// acc layout in d_ws (doubles):
//   acc1[s*64 + c]  s in 0..9  (sum:0-4, sumsq:5-9)      offset 0,    640 doubles
//   acc2[s*64 + c]  s in 0..9                             offset 640,  640 doubles

// ---------------- Pass 1: y1 = mlp_in @ W1^T + b1 ; accumulate sum/sumsq ----
__global__ __launch_bounds__(TPB) void pass1_kernel(
    const float* __restrict__ feat, const float* __restrict__ ang,
    const float* __restrict__ W1, const float* __restrict__ b1,
    double* __restrict__ acc)
{
    __shared__ float4 nd[PP];
    __shared__ float sW[25], sb[5];
    __shared__ float red[4][10];
    const int t = threadIdx.x;
    const int base = blockIdx.x * PP;

    if (t < PP) {
        float f  = feat[base + t];
        float br = ang[2*(base+t)];
        float bi = ang[2*(base+t)+1];
        nd[t] = make_float4(f, br, bi, 1.0f / (br*br + bi*bi));
    }
    if (t < 25) sW[t] = W1[t];
    if (t < 5)  sb[t] = b1[t];
    __syncthreads();

    float a[10];
#pragma unroll
    for (int k = 0; k < 10; ++k) a[k] = 0.0f;

    if (t < 250) {
        const int pi = t / 5;
        const int s  = t - pi*5;
        const float4 ni = nd[pi];
        const float fi = ni.x, ar = ni.y, ai = ni.z;
#pragma unroll
        for (int q = 0; q < 10; ++q) {
            const float4 nj = nd[s*10 + q];
            const float fj = nj.x, br = nj.y, bi = nj.z, inv = nj.w;
            const float dr = (ar*br + ai*bi) * inv;
            const float dm = (ai*br - ar*bi) * inv;
            const float df = fj - fi;
#pragma unroll
            for (int o = 0; o < 5; ++o) {
                float y = sb[o];
                y = fmaf(sW[o*5+0], fi, y);
                y = fmaf(sW[o*5+1], fj, y);
                y = fmaf(sW[o*5+2], df, y);
                y = fmaf(sW[o*5+3], dr, y);
                y = fmaf(sW[o*5+4], dm, y);
                a[o]   += y;
                a[5+o]  = fmaf(y, y, a[5+o]);
            }
        }
    }

#pragma unroll
    for (int k = 0; k < 10; ++k) {
        float v = a[k];
#pragma unroll
        for (int off = 32; off > 0; off >>= 1) v += __shfl_down(v, off, 64);
        a[k] = v;
    }
    const int lane = t & 63, wv = t >> 6;
    if (lane == 0) {
#pragma unroll
        for (int k = 0; k < 10; ++k) red[wv][k] = a[k];
    }
    __syncthreads();
    if (t < 10) {
        atomicAdd(&acc[t * NCOPY + (blockIdx.x & (NCOPY-1))],
                  (double)(red[0][t] + red[1][t] + red[2][t] + red[3][t]));
    }
}

// ---------------- Pass 2: h1 = lrelu(BN1(y1)); y2 = h1 @ W2^T + b2 ; stats --
__global__ __launch_bounds__(TPB) void pass2_kernel(
    const float* __restrict__ feat, const float* __restrict__ ang,
    const float* __restrict__ W1, const float* __restrict__ b1,
    const float* __restrict__ g1, const float* __restrict__ bt1,
    const float* __restrict__ W2, const float* __restrict__ b2,
    double* __restrict__ acc)
{
    __shared__ float4 nd[PP];
    __shared__ float sW1[25], sb1[5], sW2[25], sb2[5];
    __shared__ float sc1[5], sh1[5];
    __shared__ double tmp[10];
    __shared__ float red[4][10];
    const int t = threadIdx.x;
    const int base = blockIdx.x * PP;

    if (t < PP) {
        float f  = feat[base + t];
        float br = ang[2*(base+t)];
        float bi = ang[2*(base+t)+1];
        nd[t] = make_float4(f, br, bi, 1.0f / (br*br + bi*bi));
    }
    if (t < 25) { sW1[t] = W1[t]; sW2[t] = W2[t]; }
    if (t < 10) {
        double s = 0.0;
#pragma unroll
        for (int c = 0; c < NCOPY; ++c) s += acc[t * NCOPY + c];
        tmp[t] = s;
    }
    __syncthreads();
    if (t < 5) {
        sb1[t] = b1[t]; sb2[t] = b2[t];
        double mu  = tmp[t]   / ETOT;
        double var = tmp[5+t] / ETOT - mu * mu;
        float s = g1[t] * rsqrtf((float)var + EPSF);
        sc1[t] = s;
        sh1[t] = bt1[t] - (float)mu * s;
    }
    __syncthreads();

    float a[10];
#pragma unroll
    for (int k = 0; k < 10; ++k) a[k] = 0.0f;

    if (t < 250) {
        const int pi = t / 5;
        const int s  = t - pi*5;
        const float4 ni = nd[pi];
        const float fi = ni.x, ar = ni.y, ai = ni.z;
#pragma unroll
        for (int q = 0; q < 10; ++q) {
            const float4 nj = nd[s*10 + q];
            const float fj = nj.x, br = nj.y, bi = nj.z, inv = nj.w;
            const float dr = (ar*br + ai*bi) * inv;
            const float dm = (ai*br - ar*bi) * inv;
            const float df = fj - fi;
            float h1[5];
#pragma unroll
            for (int o = 0; o < 5; ++o) {
                float y = sb1[o];
                y = fmaf(sW1[o*5+0], fi, y);
                y = fmaf(sW1[o*5+1], fj, y);
                y = fmaf(sW1[o*5+2], df, y);
                y = fmaf(sW1[o*5+3], dr, y);
                y = fmaf(sW1[o*5+4], dm, y);
                h1[o] = lrelu(fmaf(y, sc1[o], sh1[o]));
            }
#pragma unroll
            for (int o = 0; o < 5; ++o) {
                float y = sb2[o];
                y = fmaf(sW2[o*5+0], h1[0], y);
                y = fmaf(sW2[o*5+1], h1[1], y);
                y = fmaf(sW2[o*5+2], h1[2], y);
                y = fmaf(sW2[o*5+3], h1[3], y);
                y = fmaf(sW2[o*5+4], h1[4], y);
                a[o]   += y;
                a[5+o]  = fmaf(y, y, a[5+o]);
            }
        }
    }

#pragma unroll
    for (int k = 0; k < 10; ++k) {
        float v = a[k];
#pragma unroll
        for (int off = 32; off > 0; off >>= 1) v += __shfl_down(v, off, 64);
        a[k] = v;
    }
    const int lane = t & 63, wv = t >> 6;
    if (lane == 0) {
#pragma unroll
        for (int k = 0; k < 10; ++k) red[wv][k] = a[k];
    }
    __syncthreads();
    if (t < 10) {
        atomicAdd(&acc[(10 + t) * NCOPY + (blockIdx.x & (NCOPY-1))],
                  (double)(red[0][t] + red[1][t] + red[2][t] + red[3][t]));
    }
}

// ---- Pass 3: full MLP, mean-aggregate y3 per dst, rotate, write output -----
__global__ __launch_bounds__(TPB) void pass3_kernel(
    const float* __restrict__ pt,
    const float* __restrict__ feat, const float* __restrict__ ang,
    const float* __restrict__ W1, const float* __restrict__ b1,
    const float* __restrict__ g1, const float* __restrict__ bt1,
    const float* __restrict__ W2, const float* __restrict__ b2,
    const float* __restrict__ g2, const float* __restrict__ bt2,
    const float* __restrict__ W3, const float* __restrict__ b3,
    const double* __restrict__ acc, float* __restrict__ out)
{
    __shared__ float4 nd[PP];
    __shared__ float spt[PP];
    __shared__ float sW1[25], sb1[5], sW2[25], sb2[5], sW3[25], sb3[5];
    __shared__ float sc1[5], sh1[5], sc2[5], sh2[5];
    __shared__ double tmp[20];
    __shared__ float part[250][5];
    const int t = threadIdx.x;
    const int base = blockIdx.x * PP;

    if (t < PP) {
        float f  = feat[base + t];
        float br = ang[2*(base+t)];
        float bi = ang[2*(base+t)+1];
        nd[t] = make_float4(f, br, bi, 1.0f / (br*br + bi*bi));
        spt[t] = pt[base + t];
    }
    if (t < 25) { sW1[t] = W1[t]; sW2[t] = W2[t]; sW3[t] = W3[t]; }
    if (t < 20) {
        double s = 0.0;
#pragma unroll
        for (int c = 0; c < NCOPY; ++c) s += acc[t * NCOPY + c];
        tmp[t] = s;
    }
    __syncthreads();
    if (t < 5) {
        sb1[t] = b1[t]; sb2[t] = b2[t]; sb3[t] = b3[t];
        double mu1  = tmp[t]    / ETOT;
        double var1 = tmp[5+t]  / ETOT - mu1 * mu1;
        float s1 = g1[t] * rsqrtf((float)var1 + EPSF);
        sc1[t] = s1; sh1[t] = bt1[t] - (float)mu1 * s1;
        double mu2  = tmp[10+t] / ETOT;
        double var2 = tmp[15+t] / ETOT - mu2 * mu2;
        float s2 = g2[t] * rsqrtf((float)var2 + EPSF);
        sc2[t] = s2; sh2[t] = bt2[t] - (float)mu2 * s2;
    }
    __syncthreads();

    float a[5];
#pragma unroll
    for (int k = 0; k < 5; ++k) a[k] = 0.0f;

    if (t < 250) {
        const int pi = t / 5;
        const int s  = t - pi*5;
        const float4 ni = nd[pi];
        const float fi = ni.x, ar = ni.y, ai = ni.z;
#pragma unroll
        for (int q = 0; q < 10; ++q) {
            const float4 nj = nd[s*10 + q];
            const float fj = nj.x, br = nj.y, bi = nj.z, inv = nj.w;
            const float dr = (ar*br + ai*bi) * inv;
            const float dm = (ai*br - ar*bi) * inv;
            const float df = fj - fi;
            float h1[5], h2[5];
#pragma unroll
            for (int o = 0; o < 5; ++o) {
                float y = sb1[o];
                y = fmaf(sW1[o*5+0], fi, y);
                y = fmaf(sW1[o*5+1], fj, y);
                y = fmaf(sW1[o*5+2], df, y);
                y = fmaf(sW1[o*5+3], dr, y);
                y = fmaf(sW1[o*5+4], dm, y);
                h1[o] = lrelu(fmaf(y, sc1[o], sh1[o]));
            }
#pragma unroll
            for (int o = 0; o < 5; ++o) {
                float y = sb2[o];
                y = fmaf(sW2[o*5+0], h1[0], y);
                y = fmaf(sW2[o*5+1], h1[1], y);
                y = fmaf(sW2[o*5+2], h1[2], y);
                y = fmaf(sW2[o*5+3], h1[3], y);
                y = fmaf(sW2[o*5+4], h1[4], y);
                h2[o] = lrelu(fmaf(y, sc2[o], sh2[o]));
            }
#pragma unroll
            for (int o = 0; o < 5; ++o) {
                float y = sb3[o];
                y = fmaf(sW3[o*5+0], h2[0], y);
                y = fmaf(sW3[o*5+1], h2[1], y);
                y = fmaf(sW3[o*5+2], h2[2], y);
                y = fmaf(sW3[o*5+3], h2[3], y);
                y = fmaf(sW3[o*5+4], h2[4], y);
                a[o] += y;
            }
        }
    }

    if (t < 250) {
#pragma unroll
        for (int c = 0; c < 5; ++c) part[t][c] = a[c];
    }
    __syncthreads();

    if (t < PP) {
        float m[5];
#pragma unroll
        for (int c = 0; c < 5; ++c) {
            m[c] = (part[5*t][c] + part[5*t+1][c] + part[5*t+2][c] +
                    part[5*t+3][c] + part[5*t+4][c]) * 0.02f;
        }
        const int d = base + t;
        const float4 ni = nd[t];
        const float zr = ni.y, zi = ni.z;
        float ss, cc;
        sincosf(6.2831853071795865f * m[4], &ss, &cc);
        float* o = out + (size_t)d * 7;
        o[0] = spt[t];
        o[1] = m[0];
        o[2] = m[1];
        o[3] = m[2];
        o[4] = m[3];
        o[5] = cc * zr - ss * zi;
        o[6] = cc * zi + ss * zr;
    }
}

extern "C" void kernel_launch(void* const* d_in, const int* in_sizes, int n_in,
                              void* d_out, int out_size, void* d_ws, size_t ws_size,
                              hipStream_t stream)
{
    const float* pt   = (const float*)d_in[0];
    const float* feat = (const float*)d_in[1];
    const float* ang  = (const float*)d_in[2];
    const float* W1   = (const float*)d_in[3];
    const float* b1   = (const float*)d_in[4];
    const float* g1   = (const float*)d_in[5];
    const float* bt1  = (const float*)d_in[6];
    const float* W2   = (const float*)d_in[7];
    const float* b2   = (const float*)d_in[8];
    const float* g2   = (const float*)d_in[9];
    const float* bt2  = (const float*)d_in[10];
    const float* W3   = (const float*)d_in[11];
    const float* b3   = (const float*)d_in[12];
    // d_in[13] = edge_index: structure is closed-form (dst=b*P+pi, src=b*P+pj), unused.
    float* out  = (float*)d_out;
    double* acc = (double*)d_ws;   // 1280 doubles: [0..640) pass1 stats, [640..1280) pass2

    hipMemsetAsync(d_ws, 0, 1280 * sizeof(double), stream);
    pass1_kernel<<<NBATCH, TPB, 0, stream>>>(feat, ang, W1, b1, acc);
    pass2_kernel<<<NBATCH, TPB, 0, stream>>>(feat, ang, W1, b1, g1, bt1, W2, b2, acc);
    pass3_kernel<<<NBATCH, TPB, 0, stream>>>(pt, feat, ang, W1, b1, g1, bt1, W2, b2,
                                             g2, bt2, W3, b3, acc, out);
}